// Round 20
// baseline (44.391 us; speedup 1.0000x reference)
//
#include <hip/hip_runtime.h>

#define B_TOTAL 32768
#define NROWB   128            // rows per block
#define TILE    32             // rows per tile
#define NT      4              // tiles per block

typedef __attribute__((ext_vector_type(8)))  short    bf16x8;
typedef __attribute__((ext_vector_type(4)))  float    f32x4;
typedef __attribute__((ext_vector_type(4)))  unsigned u32x4;

// round-to-nearest-even fp32 -> bf16 (weights, one-time)
__device__ __forceinline__ unsigned rne1(float f) {
    unsigned u = __builtin_bit_cast(unsigned, f);
    return (u + 0x7FFFu + ((u >> 16) & 1u)) >> 16;
}
// HW packed fp32x2 -> bf16x2 (gfx950; no builtin)
__device__ __forceinline__ unsigned cvtpk(float lo, float hi) {
    unsigned r;
    asm("v_cvt_pk_bf16_f32 %0, %1, %2" : "=v"(r) : "v"(lo), "v"(hi));
    return r;
}
__device__ __forceinline__ float fsig(float v) {
    return __fdividef(1.0f, 1.0f + __expf(-v));
}
__device__ __forceinline__ float ftanh(float v) {
    return 1.0f - __fdividef(2.0f, 1.0f + __expf(2.0f * v));
}

// Weights -> COMPOSITE gate-interleaved fragments for mfma 16x16x32 (R8's
// verified layout).  Frag F = (s*2 + tau)*8 + ks, s = 8-hcol slice 0..15.
// B-col n16 = hl*4 + g  ->  D's j-index gives a lane all 4 GATES of one hcol.
__global__ void wconv_kernel(const float* __restrict__ w1, const float* __restrict__ w2,
                             const float* __restrict__ wf, const float* __restrict__ w3,
                             u32x4* __restrict__ out) {
    int T = blockIdx.x * 256 + threadIdx.x;   // 16384 threads
    int F = T >> 6, l = T & 63;
    int s = F >> 4, tau = (F >> 3) & 1, ks = F & 7;
    int n16 = l & 15;
    int g = n16 & 3, hl = n16 >> 2;
    const float* W = (g == 0) ? w1 : (g == 1) ? w2 : (g == 2) ? wf : w3;
    const float* src = W + (s * 8 + tau * 4 + hl) * 256 + ks * 32 + (l >> 4) * 8;
    f32x4 lo = *(const f32x4*)src;
    f32x4 hi = *(const f32x4*)(src + 4);
    u32x4 r;
    r[0] = rne1(lo[0]) | (rne1(lo[1]) << 16);
    r[1] = rne1(lo[2]) | (rne1(lo[3]) << 16);
    r[2] = rne1(hi[0]) | (rne1(hi[1]) << 16);
    r[3] = rne1(hi[2]) | (rne1(hi[3]) << 16);
    out[T] = r;
}

// R20 = R19 (composite weights, 64 VGPR/wave, 4 MFMA chains, 2 blocks/CU)
// + XCD-pairing block remap (the two col-halves of a row-pair land on the
//   SAME XCD -> 2nd A-stage hits L2, FETCH back to ~stage-once)
// + c-prefetch depth-1 (R16 discipline: never a global load in the epilogue).
__global__ __launch_bounds__(512, 4) void lstm_kernel(
    const float* __restrict__ x, const float* __restrict__ h, const float* __restrict__ c,
    const bf16x8* __restrict__ wfrag,
    const float* __restrict__ b1, const float* __restrict__ b2,
    const float* __restrict__ bfv, const float* __restrict__ b3,
    float* __restrict__ out)
{
    __shared__ __align__(16) char smem[2][16384];   // 32 KB bf16 A dbuf

    // XCD-pairing remap: pair p = grp*8+slot at bids grp*16+slot and
    // grp*16+8+slot -> both = slot (mod 8) -> same XCD (8 XCDs, m09).
    const int b    = blockIdx.x;
    const int slot = b & 7;
    const int half = (b >> 3) & 1;
    const int grp  = b >> 4;
    const long row0 = (long)(grp * 8 + slot) * NROWB;
    const int cg   = half;

    const int tid  = threadIdx.x;
    const int wave = tid >> 6;                // 0..7
    const int lane = tid & 63;
    const int rb   = lane & 15;               // batch row within 16
    const int c4   = lane >> 4;               // 0..3 = local hcol
    const int s    = cg * 8 + wave;           // composite slice 0..15
    const int col0 = s * 8 + c4;              // tau=0 output col
    const int col1 = col0 + 4;                // tau=1 output col

    // ---- staging: thread owns 16 fp32 of row srow (two 8-fp32 phases) ----
    const int srow = tid >> 4;                // 0..31
    const int seg  = tid & 15;                // k-range seg*16..+16
    const int sks  = seg >> 1;                // ks of both phases
    const int smt  = srow >> 4;
    const int sr   = srow & 15;
    const int subA = (seg & 1) * 2;           // ksub of phase A (B = +1)
    const int offA = sks * 2048 + smt * 1024 + (((subA * 16 + sr) + sks) & 63) * 16;
    const int offB = sks * 2048 + smt * 1024 + ((((subA + 1) * 16 + sr) + sks) & 63) * 16;
    const float* const srcbase = (seg < 8) ? x : h;
    const int koff = (seg < 8) ? seg * 16 : seg * 16 - 128;

    f32x4 ar0, ar1;                           // 8 fp32 in flight (one phase)
    auto ISSUE = [&](int t, int ph) {
        const float* p = srcbase + (row0 + (long)t * TILE + srow) * 128 + koff + ph * 8;
        ar0 = *(const f32x4*)(p);
        ar1 = *(const f32x4*)(p + 4);
    };
    auto STORE = [&](int bb, int ph) {
        u32x4 w;
        w[0] = cvtpk(ar0[0], ar0[1]);
        w[1] = cvtpk(ar0[2], ar0[3]);
        w[2] = cvtpk(ar1[0], ar1[1]);
        w[3] = cvtpk(ar1[2], ar1[3]);
        *(u32x4*)(smem[bb & 1] + (ph ? offB : offA)) = w;
    };

    // ---- prologue: fill buf0 ----
    ISSUE(0, 0);

    bf16x8 wfr[2][8];                         // composite weights: 64 VGPRs
#pragma unroll
    for (int tau = 0; tau < 2; ++tau)
#pragma unroll
        for (int ks = 0; ks < 8; ++ks)
            wfr[tau][ks] = wfrag[(size_t)((s * 2 + tau) * 8 + ks) * 64 + lane];

    STORE(0, 0);
    ISSUE(0, 1);

    const f32x4 bias0 = (f32x4){ b1[col0], b2[col0], bfv[col0], b3[col0] };
    const f32x4 bias1 = (f32x4){ b1[col1], b2[col1], bfv[col1], b3[col1] };

    STORE(0, 1);

    // c prefetch for tile 0 (4 scalars: mt0/mt1 x col0/col1)
    float cva0 = c[(row0 + rb) * 128 + col0];
    float cvb0 = c[(row0 + rb) * 128 + col1];
    float cva1 = c[(row0 + 16 + rb) * 128 + col0];
    float cvb1 = c[(row0 + 16 + rb) * 128 + col1];

    float* out_h = out;
    float* out_c = out + (size_t)B_TOTAL * 128;

#pragma unroll 1
    for (int t = 0; t < NT; ++t) {
        asm volatile("s_waitcnt lgkmcnt(0)" ::: "memory");   // my ds_writes done
        __builtin_amdgcn_s_barrier();          // buf[t&1] complete block-wide
        __builtin_amdgcn_sched_barrier(0);

        const char* buf = smem[t & 1];
        const long gr0 = row0 + (long)t * TILE;

        // issue next tile's A phase-A and c-prefetch under the MFMA loop
        float na0, nb0, na1, nb1;
        if (t + 1 < NT) {
            ISSUE(t + 1, 0);
            const long nr = gr0 + TILE;
            na0 = c[(nr + rb) * 128 + col0];
            nb0 = c[(nr + rb) * 128 + col1];
            na1 = c[(nr + 16 + rb) * 128 + col0];
            nb1 = c[(nr + 16 + rb) * 128 + col1];
        }

        f32x4 a00 = bias0, a01 = bias1;        // mt0: tau0, tau1
        f32x4 a10 = bias0, a11 = bias1;        // mt1

        __builtin_amdgcn_s_setprio(1);
#pragma unroll
        for (int ks = 0; ks < 8; ++ks) {
            const int rot = ((lane + ks) & 63) * 16;
            bf16x8 af0 = *(const bf16x8*)(buf + ks * 2048 + rot);
            bf16x8 af1 = *(const bf16x8*)(buf + ks * 2048 + 1024 + rot);
            a00 = __builtin_amdgcn_mfma_f32_16x16x32_bf16(wfr[0][ks], af0, a00, 0, 0, 0);
            a01 = __builtin_amdgcn_mfma_f32_16x16x32_bf16(wfr[1][ks], af0, a01, 0, 0, 0);
            a10 = __builtin_amdgcn_mfma_f32_16x16x32_bf16(wfr[0][ks], af1, a10, 0, 0, 0);
            a11 = __builtin_amdgcn_mfma_f32_16x16x32_bf16(wfr[1][ks], af1, a11, 0, 0, 0);
        }
        __builtin_amdgcn_s_setprio(0);

        if (t + 1 < NT) {
            STORE(t + 1, 0);                   // ar loaded a full MFMA loop ago
            ISSUE(t + 1, 1);                   // phase-B loads under epilogue
        }

        // epilogue: lane holds all 4 gates of (row, col0) and (row, col1)
        // for rows gr0+rb (mt0) and gr0+16+rb (mt1); zero global LOADS here.
#pragma unroll
        for (int mt = 0; mt < 2; ++mt) {
            const long orow = (gr0 + mt * 16 + rb) * 128;
            const f32x4 acc0 = mt ? a10 : a00;
            const f32x4 acc1 = mt ? a11 : a01;
            const float cva = mt ? cva1 : cva0;
            const float cvb = mt ? cvb1 : cvb0;
            {
                const float G1 = fsig(acc0[0]);
                const float G2 = fsig(acc0[1]);
                const float GF = ftanh(acc0[2]);
                const float G3 = fsig(acc0[3]);
                const float nc = cva * G1 + G2 * GF;
                out_h[orow + col0] = ftanh(nc) * G3;
                out_c[orow + col0] = nc;
            }
            {
                const float G1 = fsig(acc1[0]);
                const float G2 = fsig(acc1[1]);
                const float GF = ftanh(acc1[2]);
                const float G3 = fsig(acc1[3]);
                const float nc = cvb * G1 + G2 * GF;
                out_h[orow + col1] = ftanh(nc) * G3;
                out_c[orow + col1] = nc;
            }
        }

        if (t + 1 < NT) {
            STORE(t + 1, 1);                   // before next lgkmcnt(0)+barrier
            cva0 = na0; cvb0 = nb0; cva1 = na1; cvb1 = nb1;
        }
    }
}

extern "C" void kernel_launch(void* const* d_in, const int* in_sizes, int n_in,
                              void* d_out, int out_size, void* d_ws, size_t ws_size,
                              hipStream_t stream) {
    (void)in_sizes; (void)n_in; (void)out_size; (void)ws_size;
    const float* x  = (const float*)d_in[0];
    const float* h  = (const float*)d_in[1];
    const float* c  = (const float*)d_in[2];
    const float* W1 = (const float*)d_in[3];
    const float* b1 = (const float*)d_in[4];
    const float* W2 = (const float*)d_in[5];
    const float* b2 = (const float*)d_in[6];
    const float* Wf = (const float*)d_in[7];
    const float* bf = (const float*)d_in[8];
    const float* W3 = (const float*)d_in[9];
    const float* b3 = (const float*)d_in[10];

    wconv_kernel<<<64, 256, 0, stream>>>(W1, W2, Wf, W3, (u32x4*)d_ws);
    lstm_kernel<<<B_TOTAL / NROWB * 2, 512, 0, stream>>>(
        x, h, c, (const bf16x8*)d_ws, b1, b2, bf, b3, (float*)d_out);
}

// Round 21
// 38.971 us; speedup vs baseline: 1.1391x; 1.1391x over previous
//
#include <hip/hip_runtime.h>

#define B_TOTAL 32768
#define NROWB   128            // rows per block
#define TILE    32             // rows per tile
#define NT      4              // tiles per block

typedef __attribute__((ext_vector_type(8)))  short    bf16x8;
typedef __attribute__((ext_vector_type(4)))  float    f32x4;
typedef __attribute__((ext_vector_type(4)))  unsigned u32x4;

// HW packed fp32x2 -> bf16x2 (gfx950; no builtin)
__device__ __forceinline__ unsigned cvtpk(float lo, float hi) {
    unsigned r;
    asm("v_cvt_pk_bf16_f32 %0, %1, %2" : "=v"(r) : "v"(lo), "v"(hi));
    return r;
}
__device__ __forceinline__ float fsig(float v) {
    return __fdividef(1.0f, 1.0f + __expf(-v));
}
__device__ __forceinline__ float ftanh(float v) {
    return 1.0f - __fdividef(2.0f, 1.0f + __expf(2.0f * v));
}

// R21 = R16 (best: 32.3 us) with the wconv pre-kernel FUSED into the wave
// prologue: each wave gathers its own W fragments straight from the fp32
// weights (L3-resident) and cvtpk's them into wfr -- no separate launch,
// no d_ws dependency, no cross-kernel serialization.  Fragment mapping is
// wconv's: wfr[g][ks], lane l = W_g[cs*16 + (l&15)][ks*32 + (l>>4)*8 + e].
// Also dropped: sched_barrier(0) after the barrier (schedule pinning).
__global__ __launch_bounds__(512, 2) void lstm_kernel(
    const float* __restrict__ x, const float* __restrict__ h, const float* __restrict__ c,
    const float* __restrict__ W1, const float* __restrict__ W2,
    const float* __restrict__ Wf, const float* __restrict__ W3,
    const float* __restrict__ b1, const float* __restrict__ b2,
    const float* __restrict__ bfv, const float* __restrict__ b3,
    float* __restrict__ out)
{
    __shared__ __align__(16) char smem[2][16384];   // 32 KB bf16 A dbuf

    const int tid  = threadIdx.x;
    const int wave = tid >> 6;                // col-slice cs = wave (0..7)
    const int lane = tid & 63;
    const int rb   = lane & 15;               // batch row within 16
    const int c4   = lane >> 4;               // 0..3
    const long row0 = (long)blockIdx.x * NROWB;
    const int gcol4 = wave * 16 + c4 * 4;     // 4 consecutive gate cols

    const int srow   = wave * 4 + (lane >> 4);   // staging row 0..31
    const int kchunk = lane & 15;                // 16 fp32 per chunk

    // A-staging registers: one tile in flight (16 fp32/lane)
    f32x4 ar[4];
    auto A_ISSUE = [&](int t) {
        const float* base = (kchunk < 8)
            ? (x + (row0 + (long)t * TILE + srow) * 128 + kchunk * 16)
            : (h + (row0 + (long)t * TILE + srow) * 128 + (kchunk - 8) * 16);
        ar[0] = *(const f32x4*)(base);
        ar[1] = *(const f32x4*)(base + 4);
        ar[2] = *(const f32x4*)(base + 8);
        ar[3] = *(const f32x4*)(base + 12);
    };
    auto A_STORE = [&](int b) {
        u32x4 w0, w1;
        w0[0] = cvtpk(ar[0][0], ar[0][1]);
        w0[1] = cvtpk(ar[0][2], ar[0][3]);
        w0[2] = cvtpk(ar[1][0], ar[1][1]);
        w0[3] = cvtpk(ar[1][2], ar[1][3]);
        w1[0] = cvtpk(ar[2][0], ar[2][1]);
        w1[1] = cvtpk(ar[2][2], ar[2][3]);
        w1[2] = cvtpk(ar[3][0], ar[3][1]);
        w1[3] = cvtpk(ar[3][2], ar[3][3]);
        char* dst = smem[b & 1] + (kchunk >> 1) * 2048 + srow * 64 + (kchunk & 1) * 32;
        *(u32x4*)(dst)      = w0;
        *(u32x4*)(dst + 16) = w1;
    };

    // ---- prologue ----
    A_ISSUE(0);

    // in-wave weight fragment construction (replaces wconv kernel):
    // lane reads 8 contiguous fp32 per frag, packs with 4 cvtpk.
    bf16x8 wfr[4][8];
    {
        const int wrow = wave * 16 + (lane & 15);        // n within gate
        const int kg   = (lane >> 4) * 8;                // k sub-offset
#pragma unroll
        for (int g = 0; g < 4; ++g) {
            const float* Wg = (g == 0) ? W1 : (g == 1) ? W2 : (g == 2) ? Wf : W3;
            const float* rowp = Wg + wrow * 256 + kg;
#pragma unroll
            for (int ks = 0; ks < 8; ++ks) {
                f32x4 lo = *(const f32x4*)(rowp + ks * 32);
                f32x4 hi = *(const f32x4*)(rowp + ks * 32 + 4);
                union { unsigned u[4]; bf16x8 v; } pk;
                pk.u[0] = cvtpk(lo[0], lo[1]);
                pk.u[1] = cvtpk(lo[2], lo[3]);
                pk.u[2] = cvtpk(hi[0], hi[1]);
                pk.u[3] = cvtpk(hi[2], hi[3]);
                wfr[g][ks] = pk.v;
            }
        }
    }

    f32x4 bias[4];
    bias[0] = *(const f32x4*)(b1 + gcol4);
    bias[1] = *(const f32x4*)(b2 + gcol4);
    bias[2] = *(const f32x4*)(bfv + gcol4);
    bias[3] = *(const f32x4*)(b3 + gcol4);

    A_STORE(0);                                  // tile 0 -> buf 0
    A_ISSUE(1);                                  // tile 1 in flight

    f32x4 cv0 = *(const f32x4*)(c + (row0 + rb) * 128 + gcol4);
    f32x4 cv1 = *(const f32x4*)(c + (row0 + 16 + rb) * 128 + gcol4);

    float* out_h = out;
    float* out_c = out + (size_t)B_TOTAL * 128;

#pragma unroll 1
    for (int t = 0; t < NT; ++t) {
        asm volatile("s_waitcnt lgkmcnt(0)" ::: "memory");   // my ds_writes done
        __builtin_amdgcn_s_barrier();            // buf[t&1] complete everywhere

        const char* buf = smem[t & 1];
        const long gr0 = row0 + (long)t * TILE;

        f32x4 acc[2][4];                         // [m-tile][gate], bias-init
#pragma unroll
        for (int g = 0; g < 4; ++g) { acc[0][g] = bias[g]; acc[1][g] = bias[g]; }

#pragma unroll
        for (int ks = 0; ks < 8; ++ks) {
            bf16x8 af0 = *(const bf16x8*)(buf + ks * 2048 + rb * 64 + c4 * 16);
            bf16x8 af1 = *(const bf16x8*)(buf + ks * 2048 + (16 + rb) * 64 + c4 * 16);
#pragma unroll
            for (int g = 0; g < 4; ++g) {        // swapped operands: D[gatecol][row]
                acc[0][g] = __builtin_amdgcn_mfma_f32_16x16x32_bf16(wfr[g][ks], af0, acc[0][g], 0, 0, 0);
                acc[1][g] = __builtin_amdgcn_mfma_f32_16x16x32_bf16(wfr[g][ks], af1, acc[1][g], 0, 0, 0);
            }
        }

        if (t + 1 < NT) {
            A_STORE(t + 1);
            if (t + 2 < NT) A_ISSUE(t + 2);
        }

        f32x4 ncv0, ncv1;
        if (t + 1 < NT) {
            ncv0 = *(const f32x4*)(c + (gr0 + TILE + rb) * 128 + gcol4);
            ncv1 = *(const f32x4*)(c + (gr0 + TILE + 16 + rb) * 128 + gcol4);
        }

#pragma unroll
        for (int mt = 0; mt < 2; ++mt) {
            const f32x4 cv = mt ? cv1 : cv0;
            f32x4 nh, nc;
#pragma unroll
            for (int j = 0; j < 4; ++j) {
                const float g1 = fsig(acc[mt][0][j]);
                const float g2 = fsig(acc[mt][1][j]);
                const float gf = ftanh(acc[mt][2][j]);
                const float g3 = fsig(acc[mt][3][j]);
                nc[j] = cv[j] * g1 + g2 * gf;
                nh[j] = ftanh(nc[j]) * g3;
            }
            const long o = (gr0 + mt * 16 + rb) * 128 + gcol4;
            *(f32x4*)(out_h + o) = nh;
            *(f32x4*)(out_c + o) = nc;
        }

        if (t + 1 < NT) { cv0 = ncv0; cv1 = ncv1; }
    }
}

extern "C" void kernel_launch(void* const* d_in, const int* in_sizes, int n_in,
                              void* d_out, int out_size, void* d_ws, size_t ws_size,
                              hipStream_t stream) {
    (void)in_sizes; (void)n_in; (void)out_size; (void)d_ws; (void)ws_size;
    const float* x  = (const float*)d_in[0];
    const float* h  = (const float*)d_in[1];
    const float* c  = (const float*)d_in[2];
    const float* W1 = (const float*)d_in[3];
    const float* b1 = (const float*)d_in[4];
    const float* W2 = (const float*)d_in[5];
    const float* b2 = (const float*)d_in[6];
    const float* Wf = (const float*)d_in[7];
    const float* bf = (const float*)d_in[8];
    const float* W3 = (const float*)d_in[9];
    const float* b3 = (const float*)d_in[10];

    lstm_kernel<<<B_TOTAL / NROWB, 512, 0, stream>>>(
        x, h, c, W1, W2, Wf, W3, b1, b2, bf, b3, (float*)d_out);
}

// Round 22
// 38.874 us; speedup vs baseline: 1.1419x; 1.0025x over previous
//
#include <hip/hip_runtime.h>

#define B_TOTAL 32768
#define NROWB   128            // rows per block
#define TILE    32             // rows per tile
#define NT      4              // tiles per block

typedef __attribute__((ext_vector_type(8)))  short    bf16x8;
typedef __attribute__((ext_vector_type(4)))  float    f32x4;
typedef __attribute__((ext_vector_type(4)))  unsigned u32x4;

// HW packed fp32x2 -> bf16x2 (gfx950; no builtin)
__device__ __forceinline__ unsigned cvtpk(float lo, float hi) {
    unsigned r;
    asm("v_cvt_pk_bf16_f32 %0, %1, %2" : "=v"(r) : "v"(lo), "v"(hi));
    return r;
}
__device__ __forceinline__ float fsig(float v) {
    return __fdividef(1.0f, 1.0f + __expf(-v));
}
__device__ __forceinline__ float ftanh(float v) {
    return 1.0f - __fdividef(2.0f, 1.0f + __expf(2.0f * v));
}

// R21 = R16 (best: 32.3 us) with the wconv pre-kernel FUSED into the wave
// prologue: each wave gathers its own W fragments straight from the fp32
// weights (L3-resident) and cvtpk's them into wfr -- no separate launch,
// no d_ws dependency, no cross-kernel serialization.  Fragment mapping is
// wconv's: wfr[g][ks], lane l = W_g[cs*16 + (l&15)][ks*32 + (l>>4)*8 + e].
// Also dropped: sched_barrier(0) after the barrier (schedule pinning).
__global__ __launch_bounds__(512, 2) void lstm_kernel(
    const float* __restrict__ x, const float* __restrict__ h, const float* __restrict__ c,
    const float* __restrict__ W1, const float* __restrict__ W2,
    const float* __restrict__ Wf, const float* __restrict__ W3,
    const float* __restrict__ b1, const float* __restrict__ b2,
    const float* __restrict__ bfv, const float* __restrict__ b3,
    float* __restrict__ out)
{
    __shared__ __align__(16) char smem[2][16384];   // 32 KB bf16 A dbuf

    const int tid  = threadIdx.x;
    const int wave = tid >> 6;                // col-slice cs = wave (0..7)
    const int lane = tid & 63;
    const int rb   = lane & 15;               // batch row within 16
    const int c4   = lane >> 4;               // 0..3
    const long row0 = (long)blockIdx.x * NROWB;
    const int gcol4 = wave * 16 + c4 * 4;     // 4 consecutive gate cols

    const int srow   = wave * 4 + (lane >> 4);   // staging row 0..31
    const int kchunk = lane & 15;                // 16 fp32 per chunk

    // A-staging registers: one tile in flight (16 fp32/lane)
    f32x4 ar[4];
    auto A_ISSUE = [&](int t) {
        const float* base = (kchunk < 8)
            ? (x + (row0 + (long)t * TILE + srow) * 128 + kchunk * 16)
            : (h + (row0 + (long)t * TILE + srow) * 128 + (kchunk - 8) * 16);
        ar[0] = *(const f32x4*)(base);
        ar[1] = *(const f32x4*)(base + 4);
        ar[2] = *(const f32x4*)(base + 8);
        ar[3] = *(const f32x4*)(base + 12);
    };
    auto A_STORE = [&](int b) {
        u32x4 w0, w1;
        w0[0] = cvtpk(ar[0][0], ar[0][1]);
        w0[1] = cvtpk(ar[0][2], ar[0][3]);
        w0[2] = cvtpk(ar[1][0], ar[1][1]);
        w0[3] = cvtpk(ar[1][2], ar[1][3]);
        w1[0] = cvtpk(ar[2][0], ar[2][1]);
        w1[1] = cvtpk(ar[2][2], ar[2][3]);
        w1[2] = cvtpk(ar[3][0], ar[3][1]);
        w1[3] = cvtpk(ar[3][2], ar[3][3]);
        char* dst = smem[b & 1] + (kchunk >> 1) * 2048 + srow * 64 + (kchunk & 1) * 32;
        *(u32x4*)(dst)      = w0;
        *(u32x4*)(dst + 16) = w1;
    };

    // ---- prologue ----
    A_ISSUE(0);

    // in-wave weight fragment construction (replaces wconv kernel):
    // lane reads 8 contiguous fp32 per frag, packs with 4 cvtpk.
    bf16x8 wfr[4][8];
    {
        const int wrow = wave * 16 + (lane & 15);        // n within gate
        const int kg   = (lane >> 4) * 8;                // k sub-offset
#pragma unroll
        for (int g = 0; g < 4; ++g) {
            const float* Wg = (g == 0) ? W1 : (g == 1) ? W2 : (g == 2) ? Wf : W3;
            const float* rowp = Wg + wrow * 256 + kg;
#pragma unroll
            for (int ks = 0; ks < 8; ++ks) {
                f32x4 lo = *(const f32x4*)(rowp + ks * 32);
                f32x4 hi = *(const f32x4*)(rowp + ks * 32 + 4);
                union { unsigned u[4]; bf16x8 v; } pk;
                pk.u[0] = cvtpk(lo[0], lo[1]);
                pk.u[1] = cvtpk(lo[2], lo[3]);
                pk.u[2] = cvtpk(hi[0], hi[1]);
                pk.u[3] = cvtpk(hi[2], hi[3]);
                wfr[g][ks] = pk.v;
            }
        }
    }

    f32x4 bias[4];
    bias[0] = *(const f32x4*)(b1 + gcol4);
    bias[1] = *(const f32x4*)(b2 + gcol4);
    bias[2] = *(const f32x4*)(bfv + gcol4);
    bias[3] = *(const f32x4*)(b3 + gcol4);

    A_STORE(0);                                  // tile 0 -> buf 0
    A_ISSUE(1);                                  // tile 1 in flight

    f32x4 cv0 = *(const f32x4*)(c + (row0 + rb) * 128 + gcol4);
    f32x4 cv1 = *(const f32x4*)(c + (row0 + 16 + rb) * 128 + gcol4);

    float* out_h = out;
    float* out_c = out + (size_t)B_TOTAL * 128;

#pragma unroll 1
    for (int t = 0; t < NT; ++t) {
        asm volatile("s_waitcnt lgkmcnt(0)" ::: "memory");   // my ds_writes done
        __builtin_amdgcn_s_barrier();            // buf[t&1] complete everywhere

        const char* buf = smem[t & 1];
        const long gr0 = row0 + (long)t * TILE;

        f32x4 acc[2][4];                         // [m-tile][gate], bias-init
#pragma unroll
        for (int g = 0; g < 4; ++g) { acc[0][g] = bias[g]; acc[1][g] = bias[g]; }

#pragma unroll
        for (int ks = 0; ks < 8; ++ks) {
            bf16x8 af0 = *(const bf16x8*)(buf + ks * 2048 + rb * 64 + c4 * 16);
            bf16x8 af1 = *(const bf16x8*)(buf + ks * 2048 + (16 + rb) * 64 + c4 * 16);
#pragma unroll
            for (int g = 0; g < 4; ++g) {        // swapped operands: D[gatecol][row]
                acc[0][g] = __builtin_amdgcn_mfma_f32_16x16x32_bf16(wfr[g][ks], af0, acc[0][g], 0, 0, 0);
                acc[1][g] = __builtin_amdgcn_mfma_f32_16x16x32_bf16(wfr[g][ks], af1, acc[1][g], 0, 0, 0);
            }
        }

        if (t + 1 < NT) {
            A_STORE(t + 1);
            if (t + 2 < NT) A_ISSUE(t + 2);
        }

        f32x4 ncv0, ncv1;
        if (t + 1 < NT) {
            ncv0 = *(const f32x4*)(c + (gr0 + TILE + rb) * 128 + gcol4);
            ncv1 = *(const f32x4*)(c + (gr0 + TILE + 16 + rb) * 128 + gcol4);
        }

#pragma unroll
        for (int mt = 0; mt < 2; ++mt) {
            const f32x4 cv = mt ? cv1 : cv0;
            f32x4 nh, nc;
#pragma unroll
            for (int j = 0; j < 4; ++j) {
                const float g1 = fsig(acc[mt][0][j]);
                const float g2 = fsig(acc[mt][1][j]);
                const float gf = ftanh(acc[mt][2][j]);
                const float g3 = fsig(acc[mt][3][j]);
                nc[j] = cv[j] * g1 + g2 * gf;
                nh[j] = ftanh(nc[j]) * g3;
            }
            const long o = (gr0 + mt * 16 + rb) * 128 + gcol4;
            *(f32x4*)(out_h + o) = nh;
            *(f32x4*)(out_c + o) = nc;
        }

        if (t + 1 < NT) { cv0 = ncv0; cv1 = ncv1; }
    }
}

extern "C" void kernel_launch(void* const* d_in, const int* in_sizes, int n_in,
                              void* d_out, int out_size, void* d_ws, size_t ws_size,
                              hipStream_t stream) {
    (void)in_sizes; (void)n_in; (void)out_size; (void)d_ws; (void)ws_size;
    const float* x  = (const float*)d_in[0];
    const float* h  = (const float*)d_in[1];
    const float* c  = (const float*)d_in[2];
    const float* W1 = (const float*)d_in[3];
    const float* b1 = (const float*)d_in[4];
    const float* W2 = (const float*)d_in[5];
    const float* b2 = (const float*)d_in[6];
    const float* Wf = (const float*)d_in[7];
    const float* bf = (const float*)d_in[8];
    const float* W3 = (const float*)d_in[9];
    const float* b3 = (const float*)d_in[10];

    lstm_kernel<<<B_TOTAL / NROWB, 512, 0, stream>>>(
        x, h, c, W1, W2, Wf, W3, b1, b2, bf, b3, (float*)d_out);
}

// Round 23
// 38.428 us; speedup vs baseline: 1.1552x; 1.0116x over previous
//
#include <hip/hip_runtime.h>

#define B_TOTAL 32768
#define NROWB   128            // rows per block
#define TILE    32             // rows per tile
#define NT      4              // tiles per block

typedef __attribute__((ext_vector_type(8)))  short    bf16x8;
typedef __attribute__((ext_vector_type(4)))  float    f32x4;
typedef __attribute__((ext_vector_type(4)))  unsigned u32x4;

// HW packed fp32x2 -> bf16x2 (gfx950; no builtin)
__device__ __forceinline__ unsigned cvtpk(float lo, float hi) {
    unsigned r;
    asm("v_cvt_pk_bf16_f32 %0, %1, %2" : "=v"(r) : "v"(lo), "v"(hi));
    return r;
}
__device__ __forceinline__ float fsig(float v) {
    return __fdividef(1.0f, 1.0f + __expf(-v));
}
__device__ __forceinline__ float ftanh(float v) {
    return 1.0f - __fdividef(2.0f, 1.0f + __expf(2.0f * v));
}

// R21 = R16 (best: 32.3 us) with the wconv pre-kernel FUSED into the wave
// prologue: each wave gathers its own W fragments straight from the fp32
// weights (L3-resident) and cvtpk's them into wfr -- no separate launch,
// no d_ws dependency, no cross-kernel serialization.  Fragment mapping is
// wconv's: wfr[g][ks], lane l = W_g[cs*16 + (l&15)][ks*32 + (l>>4)*8 + e].
// Also dropped: sched_barrier(0) after the barrier (schedule pinning).
__global__ __launch_bounds__(512, 2) void lstm_kernel(
    const float* __restrict__ x, const float* __restrict__ h, const float* __restrict__ c,
    const float* __restrict__ W1, const float* __restrict__ W2,
    const float* __restrict__ Wf, const float* __restrict__ W3,
    const float* __restrict__ b1, const float* __restrict__ b2,
    const float* __restrict__ bfv, const float* __restrict__ b3,
    float* __restrict__ out)
{
    __shared__ __align__(16) char smem[2][16384];   // 32 KB bf16 A dbuf

    const int tid  = threadIdx.x;
    const int wave = tid >> 6;                // col-slice cs = wave (0..7)
    const int lane = tid & 63;
    const int rb   = lane & 15;               // batch row within 16
    const int c4   = lane >> 4;               // 0..3
    const long row0 = (long)blockIdx.x * NROWB;
    const int gcol4 = wave * 16 + c4 * 4;     // 4 consecutive gate cols

    const int srow   = wave * 4 + (lane >> 4);   // staging row 0..31
    const int kchunk = lane & 15;                // 16 fp32 per chunk

    // A-staging registers: one tile in flight (16 fp32/lane)
    f32x4 ar[4];
    auto A_ISSUE = [&](int t) {
        const float* base = (kchunk < 8)
            ? (x + (row0 + (long)t * TILE + srow) * 128 + kchunk * 16)
            : (h + (row0 + (long)t * TILE + srow) * 128 + (kchunk - 8) * 16);
        ar[0] = *(const f32x4*)(base);
        ar[1] = *(const f32x4*)(base + 4);
        ar[2] = *(const f32x4*)(base + 8);
        ar[3] = *(const f32x4*)(base + 12);
    };
    auto A_STORE = [&](int b) {
        u32x4 w0, w1;
        w0[0] = cvtpk(ar[0][0], ar[0][1]);
        w0[1] = cvtpk(ar[0][2], ar[0][3]);
        w0[2] = cvtpk(ar[1][0], ar[1][1]);
        w0[3] = cvtpk(ar[1][2], ar[1][3]);
        w1[0] = cvtpk(ar[2][0], ar[2][1]);
        w1[1] = cvtpk(ar[2][2], ar[2][3]);
        w1[2] = cvtpk(ar[3][0], ar[3][1]);
        w1[3] = cvtpk(ar[3][2], ar[3][3]);
        char* dst = smem[b & 1] + (kchunk >> 1) * 2048 + srow * 64 + (kchunk & 1) * 32;
        *(u32x4*)(dst)      = w0;
        *(u32x4*)(dst + 16) = w1;
    };

    // ---- prologue ----
    A_ISSUE(0);

    // in-wave weight fragment construction (replaces wconv kernel):
    // lane reads 8 contiguous fp32 per frag, packs with 4 cvtpk.
    bf16x8 wfr[4][8];
    {
        const int wrow = wave * 16 + (lane & 15);        // n within gate
        const int kg   = (lane >> 4) * 8;                // k sub-offset
#pragma unroll
        for (int g = 0; g < 4; ++g) {
            const float* Wg = (g == 0) ? W1 : (g == 1) ? W2 : (g == 2) ? Wf : W3;
            const float* rowp = Wg + wrow * 256 + kg;
#pragma unroll
            for (int ks = 0; ks < 8; ++ks) {
                f32x4 lo = *(const f32x4*)(rowp + ks * 32);
                f32x4 hi = *(const f32x4*)(rowp + ks * 32 + 4);
                union { unsigned u[4]; bf16x8 v; } pk;
                pk.u[0] = cvtpk(lo[0], lo[1]);
                pk.u[1] = cvtpk(lo[2], lo[3]);
                pk.u[2] = cvtpk(hi[0], hi[1]);
                pk.u[3] = cvtpk(hi[2], hi[3]);
                wfr[g][ks] = pk.v;
            }
        }
    }

    f32x4 bias[4];
    bias[0] = *(const f32x4*)(b1 + gcol4);
    bias[1] = *(const f32x4*)(b2 + gcol4);
    bias[2] = *(const f32x4*)(bfv + gcol4);
    bias[3] = *(const f32x4*)(b3 + gcol4);

    A_STORE(0);                                  // tile 0 -> buf 0
    A_ISSUE(1);                                  // tile 1 in flight

    f32x4 cv0 = *(const f32x4*)(c + (row0 + rb) * 128 + gcol4);
    f32x4 cv1 = *(const f32x4*)(c + (row0 + 16 + rb) * 128 + gcol4);

    float* out_h = out;
    float* out_c = out + (size_t)B_TOTAL * 128;

#pragma unroll 1
    for (int t = 0; t < NT; ++t) {
        asm volatile("s_waitcnt lgkmcnt(0)" ::: "memory");   // my ds_writes done
        __builtin_amdgcn_s_barrier();            // buf[t&1] complete everywhere

        const char* buf = smem[t & 1];
        const long gr0 = row0 + (long)t * TILE;

        f32x4 acc[2][4];                         // [m-tile][gate], bias-init
#pragma unroll
        for (int g = 0; g < 4; ++g) { acc[0][g] = bias[g]; acc[1][g] = bias[g]; }

#pragma unroll
        for (int ks = 0; ks < 8; ++ks) {
            bf16x8 af0 = *(const bf16x8*)(buf + ks * 2048 + rb * 64 + c4 * 16);
            bf16x8 af1 = *(const bf16x8*)(buf + ks * 2048 + (16 + rb) * 64 + c4 * 16);
#pragma unroll
            for (int g = 0; g < 4; ++g) {        // swapped operands: D[gatecol][row]
                acc[0][g] = __builtin_amdgcn_mfma_f32_16x16x32_bf16(wfr[g][ks], af0, acc[0][g], 0, 0, 0);
                acc[1][g] = __builtin_amdgcn_mfma_f32_16x16x32_bf16(wfr[g][ks], af1, acc[1][g], 0, 0, 0);
            }
        }

        if (t + 1 < NT) {
            A_STORE(t + 1);
            if (t + 2 < NT) A_ISSUE(t + 2);
        }

        f32x4 ncv0, ncv1;
        if (t + 1 < NT) {
            ncv0 = *(const f32x4*)(c + (gr0 + TILE + rb) * 128 + gcol4);
            ncv1 = *(const f32x4*)(c + (gr0 + TILE + 16 + rb) * 128 + gcol4);
        }

#pragma unroll
        for (int mt = 0; mt < 2; ++mt) {
            const f32x4 cv = mt ? cv1 : cv0;
            f32x4 nh, nc;
#pragma unroll
            for (int j = 0; j < 4; ++j) {
                const float g1 = fsig(acc[mt][0][j]);
                const float g2 = fsig(acc[mt][1][j]);
                const float gf = ftanh(acc[mt][2][j]);
                const float g3 = fsig(acc[mt][3][j]);
                nc[j] = cv[j] * g1 + g2 * gf;
                nh[j] = ftanh(nc[j]) * g3;
            }
            const long o = (gr0 + mt * 16 + rb) * 128 + gcol4;
            *(f32x4*)(out_h + o) = nh;
            *(f32x4*)(out_c + o) = nc;
        }

        if (t + 1 < NT) { cv0 = ncv0; cv1 = ncv1; }
    }
}

extern "C" void kernel_launch(void* const* d_in, const int* in_sizes, int n_in,
                              void* d_out, int out_size, void* d_ws, size_t ws_size,
                              hipStream_t stream) {
    (void)in_sizes; (void)n_in; (void)out_size; (void)d_ws; (void)ws_size;
    const float* x  = (const float*)d_in[0];
    const float* h  = (const float*)d_in[1];
    const float* c  = (const float*)d_in[2];
    const float* W1 = (const float*)d_in[3];
    const float* b1 = (const float*)d_in[4];
    const float* W2 = (const float*)d_in[5];
    const float* b2 = (const float*)d_in[6];
    const float* Wf = (const float*)d_in[7];
    const float* bf = (const float*)d_in[8];
    const float* W3 = (const float*)d_in[9];
    const float* b3 = (const float*)d_in[10];

    lstm_kernel<<<B_TOTAL / NROWB, 512, 0, stream>>>(
        x, h, c, W1, W2, Wf, W3, b1, b2, bf, b3, (float*)d_out);
}

// Round 24
// 32.435 us; speedup vs baseline: 1.3686x; 1.1848x over previous
//
#include <hip/hip_runtime.h>

#define B_TOTAL 32768
#define NROWB   128            // rows per block
#define TILE    32             // rows per tile
#define NT      4              // tiles per block

typedef __attribute__((ext_vector_type(8)))  short    bf16x8;
typedef __attribute__((ext_vector_type(4)))  float    f32x4;
typedef __attribute__((ext_vector_type(4)))  unsigned u32x4;

// round-to-nearest-even fp32 -> bf16 (weights, one-time)
__device__ __forceinline__ unsigned rne1(float f) {
    unsigned u = __builtin_bit_cast(unsigned, f);
    return (u + 0x7FFFu + ((u >> 16) & 1u)) >> 16;
}
// HW packed fp32x2 -> bf16x2 (gfx950; no builtin)
__device__ __forceinline__ unsigned cvtpk(float lo, float hi) {
    unsigned r;
    asm("v_cvt_pk_bf16_f32 %0, %1, %2" : "=v"(r) : "v"(lo), "v"(hi));
    return r;
}
__device__ __forceinline__ float fsig(float v) {
    return __fdividef(1.0f, 1.0f + __expf(-v));
}
__device__ __forceinline__ float ftanh(float v) {
    return 1.0f - __fdividef(2.0f, 1.0f + __expf(2.0f * v));
}

// Weights -> fragment-linear bf16 for mfma 16x16x32 (R5 layout, cs = 0..7).
// Frag F = cs*32 + g*8 + ks; lane l: W_g[n = cs*16 + (l&15)][k = ks*32 + (l>>4)*8 + e]
__global__ void wconv_kernel(const float* __restrict__ w1, const float* __restrict__ w2,
                             const float* __restrict__ wf, const float* __restrict__ w3,
                             u32x4* __restrict__ out) {
    int T = blockIdx.x * 256 + threadIdx.x;
    int F = T >> 6, l = T & 63;
    int cs = F >> 5, g = (F >> 3) & 3, ks = F & 7;
    const float* W = (g == 0) ? w1 : (g == 1) ? w2 : (g == 2) ? wf : w3;
    const float* s = W + (cs * 16 + (l & 15)) * 256 + ks * 32 + (l >> 4) * 8;
    f32x4 lo = *(const f32x4*)s;
    f32x4 hi = *(const f32x4*)(s + 4);
    u32x4 r;
    r[0] = rne1(lo[0]) | (rne1(lo[1]) << 16);
    r[1] = rne1(lo[2]) | (rne1(lo[3]) << 16);
    r[2] = rne1(hi[0]) | (rne1(hi[1]) << 16);
    r[3] = rne1(hi[2]) | (rne1(hi[3]) << 16);
    out[T] = r;
}

// R24 = exact R16 revert (best measured: 32.3 us).
// bf16 LDS staging -- convert ONCE per element (reg-staged), read ONCE.
// 256 blocks x 512 thr (8 waves = all 128 cols), 128 rows as 4 tiles of 32.
// bf16 A-tile layout [8 ks][32 rows][64 B]; hot loop per wave-tile:
// 16 ds_read_b128 + 64 MFMA, zero cvtpk. Resident weights wfr[4][8].
// Sync: raw s_barrier + lgkmcnt(0); A-loads are compiler-tracked registers,
// issued one full body ahead.
__global__ __launch_bounds__(512, 2) void lstm_kernel(
    const float* __restrict__ x, const float* __restrict__ h, const float* __restrict__ c,
    const bf16x8* __restrict__ wfrag,
    const float* __restrict__ b1, const float* __restrict__ b2,
    const float* __restrict__ bfv, const float* __restrict__ b3,
    float* __restrict__ out)
{
    __shared__ __align__(16) char smem[2][16384];   // 32 KB bf16 A dbuf

    const int tid  = threadIdx.x;
    const int wave = tid >> 6;                // col-slice cs = wave (0..7)
    const int lane = tid & 63;
    const int rb   = lane & 15;               // batch row within 16
    const int c4   = lane >> 4;               // 0..3
    const long row0 = (long)blockIdx.x * NROWB;
    const int gcol4 = wave * 16 + c4 * 4;     // 4 consecutive gate cols

    const int srow   = wave * 4 + (lane >> 4);   // staging row 0..31
    const int kchunk = lane & 15;                // 16 fp32 per chunk

    // A-staging registers: one tile in flight (16 fp32/lane)
    f32x4 ar[4];
    auto A_ISSUE = [&](int t) {                  // issue global loads, tile t
        const float* base = (kchunk < 8)
            ? (x + (row0 + (long)t * TILE + srow) * 128 + kchunk * 16)
            : (h + (row0 + (long)t * TILE + srow) * 128 + (kchunk - 8) * 16);
        ar[0] = *(const f32x4*)(base);
        ar[1] = *(const f32x4*)(base + 4);
        ar[2] = *(const f32x4*)(base + 8);
        ar[3] = *(const f32x4*)(base + 12);
    };
    auto A_STORE = [&](int b) {                  // cvtpk + ds_write to buf b&1
        u32x4 w0, w1;
        w0[0] = cvtpk(ar[0][0], ar[0][1]);
        w0[1] = cvtpk(ar[0][2], ar[0][3]);
        w0[2] = cvtpk(ar[1][0], ar[1][1]);
        w0[3] = cvtpk(ar[1][2], ar[1][3]);
        w1[0] = cvtpk(ar[2][0], ar[2][1]);
        w1[1] = cvtpk(ar[2][2], ar[2][3]);
        w1[2] = cvtpk(ar[3][0], ar[3][1]);
        w1[3] = cvtpk(ar[3][2], ar[3][3]);
        // dest: ks = kchunk>>1, 32B half = kchunk&1  ([ks][row][64B] layout)
        char* dst = smem[b & 1] + (kchunk >> 1) * 2048 + srow * 64 + (kchunk & 1) * 32;
        *(u32x4*)(dst)      = w0;
        *(u32x4*)(dst + 16) = w1;
    };

    // ---- prologue ----
    A_ISSUE(0);

    bf16x8 wfr[4][8];                            // resident weights, 128 VGPR
#pragma unroll
    for (int g = 0; g < 4; ++g)
#pragma unroll
        for (int ks = 0; ks < 8; ++ks)
            wfr[g][ks] = wfrag[(size_t)(wave * 32 + g * 8 + ks) * 64 + lane];

    f32x4 bias[4];
    bias[0] = *(const f32x4*)(b1 + gcol4);
    bias[1] = *(const f32x4*)(b2 + gcol4);
    bias[2] = *(const f32x4*)(bfv + gcol4);
    bias[3] = *(const f32x4*)(b3 + gcol4);

    A_STORE(0);                                  // tile 0 -> buf 0
    A_ISSUE(1);                                  // tile 1 in flight

    f32x4 cv0 = *(const f32x4*)(c + (row0 + rb) * 128 + gcol4);
    f32x4 cv1 = *(const f32x4*)(c + (row0 + 16 + rb) * 128 + gcol4);

    float* out_h = out;
    float* out_c = out + (size_t)B_TOTAL * 128;

#pragma unroll 1
    for (int t = 0; t < NT; ++t) {
        asm volatile("s_waitcnt lgkmcnt(0)" ::: "memory");   // my ds_writes done
        __builtin_amdgcn_s_barrier();            // buf[t&1] complete everywhere
        __builtin_amdgcn_sched_barrier(0);

        const char* buf = smem[t & 1];
        const long gr0 = row0 + (long)t * TILE;

        f32x4 acc[2][4];                         // [m-tile][gate], bias-init
#pragma unroll
        for (int g = 0; g < 4; ++g) { acc[0][g] = bias[g]; acc[1][g] = bias[g]; }

#pragma unroll
        for (int ks = 0; ks < 8; ++ks) {
            // contiguous 1KB wave-reads, immediate offsets
            bf16x8 af0 = *(const bf16x8*)(buf + ks * 2048 + rb * 64 + c4 * 16);
            bf16x8 af1 = *(const bf16x8*)(buf + ks * 2048 + (16 + rb) * 64 + c4 * 16);
#pragma unroll
            for (int g = 0; g < 4; ++g) {        // swapped operands: D[gatecol][row]
                acc[0][g] = __builtin_amdgcn_mfma_f32_16x16x32_bf16(wfr[g][ks], af0, acc[0][g], 0, 0, 0);
                acc[1][g] = __builtin_amdgcn_mfma_f32_16x16x32_bf16(wfr[g][ks], af1, acc[1][g], 0, 0, 0);
            }
        }

        // stage t+1 into the other buffer, then start tile t+2's loads
        if (t + 1 < NT) {
            A_STORE(t + 1);
            if (t + 2 < NT) A_ISSUE(t + 2);
        }

        // c prefetch for next tile
        f32x4 ncv0, ncv1;
        if (t + 1 < NT) {
            ncv0 = *(const f32x4*)(c + (gr0 + TILE + rb) * 128 + gcol4);
            ncv1 = *(const f32x4*)(c + (gr0 + TILE + 16 + rb) * 128 + gcol4);
        }

        // epilogue: in-register combine, float4 stores
#pragma unroll
        for (int mt = 0; mt < 2; ++mt) {
            const f32x4 cv = mt ? cv1 : cv0;
            f32x4 nh, nc;
#pragma unroll
            for (int j = 0; j < 4; ++j) {
                const float g1 = fsig(acc[mt][0][j]);
                const float g2 = fsig(acc[mt][1][j]);
                const float gf = ftanh(acc[mt][2][j]);
                const float g3 = fsig(acc[mt][3][j]);
                nc[j] = cv[j] * g1 + g2 * gf;
                nh[j] = ftanh(nc[j]) * g3;
            }
            const long o = (gr0 + mt * 16 + rb) * 128 + gcol4;
            *(f32x4*)(out_h + o) = nh;
            *(f32x4*)(out_c + o) = nc;
        }

        if (t + 1 < NT) { cv0 = ncv0; cv1 = ncv1; }
    }
}

extern "C" void kernel_launch(void* const* d_in, const int* in_sizes, int n_in,
                              void* d_out, int out_size, void* d_ws, size_t ws_size,
                              hipStream_t stream) {
    (void)in_sizes; (void)n_in; (void)out_size; (void)ws_size;
    const float* x  = (const float*)d_in[0];
    const float* h  = (const float*)d_in[1];
    const float* c  = (const float*)d_in[2];
    const float* W1 = (const float*)d_in[3];
    const float* b1 = (const float*)d_in[4];
    const float* W2 = (const float*)d_in[5];
    const float* b2 = (const float*)d_in[6];
    const float* Wf = (const float*)d_in[7];
    const float* bf = (const float*)d_in[8];
    const float* W3 = (const float*)d_in[9];
    const float* b3 = (const float*)d_in[10];

    wconv_kernel<<<64, 256, 0, stream>>>(W1, W2, Wf, W3, (u32x4*)d_ws);
    lstm_kernel<<<B_TOTAL / NROWB, 512, 0, stream>>>(
        x, h, c, (const bf16x8*)d_ws, b1, b2, bf, b3, (float*)d_out);
}